// Round 5
// baseline (211.845 us; speedup 1.0000x reference)
//
#include <hip/hip_runtime.h>
#include <hip/hip_bf16.h>

// Problem: out[32768,128] = sigmoid(x[32768,1024] @ W[1024,128] + b[128]), all fp32.
// R5: barrier-free streaming k-loop. W (bf16, swizzled) resident in LDS in two
//     128KB k-halves staged inside ONE persistent block (one restage barrier per
//     512 k, vs R4's barrier per 256 cols x 8 steps). A-stream is the only vm
//     traffic, prefetched 4 steps deep with constant-indexed buffers (spill-proof).
//     Grid = 256 (1 block/CU), block = 512 thr = 8 waves = 2 waves/SIMD.

typedef __bf16 bf16x8 __attribute__((ext_vector_type(8)));
typedef float  f32x4  __attribute__((ext_vector_type(4)));

#define DIM   1024
#define NT    128
#define BATCH 32768

// ---------------------------------------------------------------------------
// Prep: W[k][n] fp32 -> bf16 in B-fragment order.
// wsW[ ((s*8 + c)*64 + lane)*8 + j ] = W[ s*32 + (lane>>4)*8 + j ][ c*16 + (lane&15) ]
// ---------------------------------------------------------------------------
__global__ __launch_bounds__(256) void prep_w(const float* __restrict__ W,
                                              __bf16* __restrict__ wsW) {
    int idx = blockIdx.x * 256 + threadIdx.x;   // 0 .. 131071
    int j = idx & 7;
    int l = (idx >> 3) & 63;
    int c = (idx >> 9) & 7;
    int s = idx >> 12;
    int k = s * 32 + (l >> 4) * 8 + j;
    int n = c * 16 + (l & 15);
    wsW[idx] = (__bf16)W[k * NT + n];
}

__device__ __forceinline__ bf16x8 cvt_bf16x8(float4 a0, float4 a1) {
    bf16x8 af;
    af[0] = (__bf16)a0.x; af[1] = (__bf16)a0.y;
    af[2] = (__bf16)a0.z; af[3] = (__bf16)a0.w;
    af[4] = (__bf16)a1.x; af[5] = (__bf16)a1.y;
    af[6] = (__bf16)a1.z; af[7] = (__bf16)a1.w;
    return af;
}

// ---------------------------------------------------------------------------
// Main: grid = 256 blocks (1/CU), block = 512 threads = 8 waves.
// Wave tile 16 rows x 128 cols (acc = 32 VGPR); block = 128 rows.
// LDS: 8192 frags (128 KB) = one k-half of W; restaged once mid-kernel.
// A-frag (16x16x32): lane holds A[m = lane&15][k = (lane>>4)*8 + j]
// B-frag:            lane holds B[k = (lane>>4)*8 + j][n = lane&15]
// C/D:               col = lane&15, row = (lane>>4)*4 + reg
// ---------------------------------------------------------------------------
__global__ __launch_bounds__(512, 2) void gemm_bias_sigmoid(
        const float* __restrict__ x,
        const __hip_bfloat16* __restrict__ wsWh,
        const float* __restrict__ bias,
        float* __restrict__ out) {
    const bf16x8* __restrict__ wsW8 = (const bf16x8*)wsWh;  // 16384 frag units
    __shared__ bf16x8 ldsW[8192];                           // 128 KB

    const int tid  = threadIdx.x;
    const int lane = tid & 63;
    const int wave = tid >> 6;       // 0..7
    const int q    = lane >> 4;
    const int r    = lane & 15;
    const int row0 = blockIdx.x * 128 + wave * 16;

    const float* xA = x + (size_t)(row0 + r) * DIM + q * 8;

    f32x4 acc[8];
#pragma unroll
    for (int c = 0; c < 8; ++c)
        acc[c] = (f32x4){0.f, 0.f, 0.f, 0.f};

    // A prefetch ring, depth 4 k-steps; all indices become constants after unroll.
    float4 A[4][2];
#pragma unroll
    for (int i = 0; i < 4; ++i) {
        A[i][0] = *(const float4*)(xA + (size_t)i * 32);
        A[i][1] = *(const float4*)(xA + (size_t)i * 32 + 4);
    }

    // Stage W half 0 (128 KB, linear, 16B/thread x 16 — conflict-free).
#pragma unroll
    for (int i = 0; i < 16; ++i)
        ldsW[tid + i * 512] = wsW8[tid + i * 512];
    __syncthreads();

#pragma unroll
    for (int h = 0; h < 2; ++h) {
        if (h == 1) {
            __syncthreads();   // all waves done reading half-0 frags
#pragma unroll
            for (int i = 0; i < 16; ++i)
                ldsW[tid + i * 512] = wsW8[8192 + tid + i * 512];
            __syncthreads();   // half-1 staging visible
        }
#pragma unroll
        for (int sl = 0; sl < 16; ++sl) {
            const int s   = h * 16 + sl;   // global k-step, constant after unroll
            const int buf = s & 3;

            const bf16x8 af = cvt_bf16x8(A[buf][0], A[buf][1]);

            // reload this ring slot for step s+4 (A-stream is continuous in k,
            // crossing the half boundary freely — it lives in registers)
            if (s + 4 < 32) {
                A[buf][0] = *(const float4*)(xA + (size_t)(s + 4) * 32);
                A[buf][1] = *(const float4*)(xA + (size_t)(s + 4) * 32 + 4);
            }

#pragma unroll
            for (int c = 0; c < 8; ++c) {
                const bf16x8 bf = ldsW[(sl * 8 + c) * 64 + lane];
                acc[c] = __builtin_amdgcn_mfma_f32_16x16x32_bf16(af, bf, acc[c], 0, 0, 0);
            }
        }
    }

    // ---- epilogue: bias + sigmoid + store ----
#pragma unroll
    for (int c = 0; c < 8; ++c) {
        const float bv = bias[c * 16 + r];
#pragma unroll
        for (int reg = 0; reg < 4; ++reg) {
            const int row = row0 + q * 4 + reg;
            float v = acc[c][reg] + bv;
            v = 1.0f / (1.0f + __expf(-v));
            out[(size_t)row * NT + c * 16 + r] = v;
        }
    }
}

extern "C" void kernel_launch(void* const* d_in, const int* in_sizes, int n_in,
                              void* d_out, int out_size, void* d_ws, size_t ws_size,
                              hipStream_t stream) {
    const float* x = (const float*)d_in[0];   // [32768,1024]
    const float* W = (const float*)d_in[1];   // [1024,128]
    const float* b = (const float*)d_in[2];   // [128]
    float* out     = (float*)d_out;           // [32768,128]
    __bf16* wsW    = (__bf16*)d_ws;           // 256 KB swizzled bf16 W

    prep_w<<<DIM * NT / 256, 256, 0, stream>>>(W, wsW);
    gemm_bias_sigmoid<<<BATCH / 128, 512, 0, stream>>>(
        x, (const __hip_bfloat16*)wsW, b, out);
}

// Round 6
// 210.288 us; speedup vs baseline: 1.0074x; 1.0074x over previous
//
#include <hip/hip_runtime.h>
#include <hip/hip_bf16.h>

// Problem: out[32768,128] = sigmoid(x[32768,1024] @ W[1024,128] + b[128]), all fp32.
// R6: m97-style software pipeline. Chunk = 2 k-steps. Per chunk:
//   - W chunk (16KB, bf16 frag-linear) staged via global_load_lds (no VGPR trip)
//   - A chunk (64 rows x 64 k) loaded as contiguous float4s (4 rows x 256B full
//     lines per wave-inst instead of 16-row 4KB-stride gathers), cvt to bf16 ONCE,
//     ds_write into padded tile (row stride 136B -> conflict-free b128 frag reads)
//   - double-buffered both, ONE barrier per chunk; loads issued a full chunk ahead
// Block = 256 thr (4 waves x 16 rows), grid = 512 -> 2 blocks/CU, LDS 50176B.

typedef __bf16 bf16x8 __attribute__((ext_vector_type(8)));
typedef __bf16 bf16x4 __attribute__((ext_vector_type(4)));
typedef float  f32x4  __attribute__((ext_vector_type(4)));
typedef unsigned int u32_as1 __attribute__((address_space(1)));
typedef unsigned int u32_as3 __attribute__((address_space(3)));

#define DIM   1024
#define NT    128
#define BATCH 32768

// LDS layout (bytes):
//   Wbuf[2]: 0, 16384          (each 16KB = 1024 frags of 16B, frag-linear)
//   Abuf[2]: 32768, 41472      (each 64 rows x 136B = 8704B)
#define LDS_BYTES 50176
#define A_OFS     32768u
#define A_STRIDE  136u

// ---------------------------------------------------------------------------
// Prep: W[k][n] fp32 -> bf16 in B-fragment order.
// wsW[ ((s*8 + c)*64 + lane)*8 + j ] = W[ s*32 + (lane>>4)*8 + j ][ c*16 + (lane&15) ]
// ---------------------------------------------------------------------------
__global__ __launch_bounds__(256) void prep_w(const float* __restrict__ W,
                                              __bf16* __restrict__ wsW) {
    int idx = blockIdx.x * 256 + threadIdx.x;   // 0 .. 131071
    int j = idx & 7;
    int l = (idx >> 3) & 63;
    int c = (idx >> 9) & 7;
    int s = idx >> 12;
    int k = s * 32 + (l >> 4) * 8 + j;
    int n = c * 16 + (l & 15);
    wsW[idx] = (__bf16)W[k * NT + n];
}

// ---------------------------------------------------------------------------
// Main GEMM. Wave tile 16 rows x 128 cols (acc = 32 VGPR).
// A-frag (16x16x32): lane holds A[m = lane&15][k = (lane>>4)*8 + j]
// B-frag:            lane holds B[k = (lane>>4)*8 + j][n = lane&15]
// C/D:               col = lane&15, row = (lane>>4)*4 + reg
// ---------------------------------------------------------------------------
__global__ __launch_bounds__(256) void gemm_bias_sigmoid(
        const float* __restrict__ x,
        const __hip_bfloat16* __restrict__ wsWh,
        const float* __restrict__ bias,
        float* __restrict__ out) {
    __shared__ __align__(16) unsigned char lds[LDS_BYTES];
    const bf16x8* __restrict__ wsW8 = (const bf16x8*)wsWh;  // 16384 frags

    const int tid  = threadIdx.x;
    const int lane = tid & 63;
    const int wave = tid >> 6;
    const int q    = lane >> 4;
    const int r    = lane & 15;
    const int row0 = blockIdx.x * 64;

    // A staging mapping: thread t covers rows rbase + i*16 (i=0..3), k-span kk4..kk4+3
    const int rbase = tid >> 4;        // 0..15
    const int kk4   = (tid & 15) * 4;  // 0..60

    f32x4 acc[8];
#pragma unroll
    for (int c = 0; c < 8; ++c)
        acc[c] = (f32x4){0.f, 0.f, 0.f, 0.f};

    float4 areg[4];   // staged A in regs; constant-indexed (unrolled) only

    // ---------------- prologue: stage chunk 0 ----------------
#pragma unroll
    for (int i = 0; i < 4; ++i) {
        const bf16x8* g = wsW8 + (i * 256 + tid);
        __builtin_amdgcn_global_load_lds(
            (const u32_as1*)g,
            (u32_as3*)(lds + (unsigned)((i * 256 + wave * 64) * 16)),
            16, 0, 0);
    }
#pragma unroll
    for (int i = 0; i < 4; ++i)
        areg[i] = *(const float4*)(x + (size_t)(row0 + rbase + i * 16) * DIM + kk4);
#pragma unroll
    for (int i = 0; i < 4; ++i) {
        bf16x4 v;
        v[0] = (__bf16)areg[i].x; v[1] = (__bf16)areg[i].y;
        v[2] = (__bf16)areg[i].z; v[3] = (__bf16)areg[i].w;
        *(bf16x4*)(lds + A_OFS + (unsigned)(rbase + i * 16) * A_STRIDE + (unsigned)kk4 * 2) = v;
    }
    __syncthreads();

    // ---------------- main loop: 16 chunks of 2 k-steps ----------------
#pragma unroll
    for (int c = 0; c < 16; ++c) {
        const int cur = c & 1;
        const int nxt = cur ^ 1;
        const unsigned Wc = 16384u * (unsigned)cur;
        const unsigned Ac = A_OFS + 8704u * (unsigned)cur;

        // issue next chunk's staging loads (full chunk of latency coverage)
        if (c < 15) {
#pragma unroll
            for (int i = 0; i < 4; ++i) {
                const bf16x8* g = wsW8 + ((c + 1) * 1024 + i * 256 + tid);
                __builtin_amdgcn_global_load_lds(
                    (const u32_as1*)g,
                    (u32_as3*)(lds + 16384u * (unsigned)nxt +
                               (unsigned)((i * 256 + wave * 64) * 16)),
                    16, 0, 0);
            }
#pragma unroll
            for (int i = 0; i < 4; ++i)
                areg[i] = *(const float4*)(x + (size_t)(row0 + rbase + i * 16) * DIM +
                                           (c + 1) * 64 + kk4);
        }

        // compute chunk c: k-steps 2c, 2c+1
#pragma unroll
        for (int sl = 0; sl < 2; ++sl) {
            const bf16x8 af = *(const bf16x8*)(lds + Ac +
                (unsigned)(wave * 16 + r) * A_STRIDE + (unsigned)(sl * 64 + q * 16));
#pragma unroll
            for (int cc = 0; cc < 8; ++cc) {
                const bf16x8 bf = *(const bf16x8*)(lds + Wc +
                    (unsigned)(((sl * 8 + cc) * 64 + lane) * 16));
                acc[cc] = __builtin_amdgcn_mfma_f32_16x16x32_bf16(af, bf, acc[cc], 0, 0, 0);
            }
        }

        // write next A chunk to the other buffer
        if (c < 15) {
#pragma unroll
            for (int i = 0; i < 4; ++i) {
                bf16x4 v;
                v[0] = (__bf16)areg[i].x; v[1] = (__bf16)areg[i].y;
                v[2] = (__bf16)areg[i].z; v[3] = (__bf16)areg[i].w;
                *(bf16x4*)(lds + A_OFS + 8704u * (unsigned)nxt +
                           (unsigned)(rbase + i * 16) * A_STRIDE + (unsigned)kk4 * 2) = v;
            }
        }
        __syncthreads();
    }

    // ---------------- epilogue: bias + sigmoid + store ----------------
    const int wrow = row0 + wave * 16;
#pragma unroll
    for (int c = 0; c < 8; ++c) {
        const float bv = bias[c * 16 + r];
#pragma unroll
        for (int reg = 0; reg < 4; ++reg) {
            const int row = wrow + q * 4 + reg;
            float v = acc[c][reg] + bv;
            v = 1.0f / (1.0f + __expf(-v));
            out[(size_t)row * NT + c * 16 + r] = v;
        }
    }
}

extern "C" void kernel_launch(void* const* d_in, const int* in_sizes, int n_in,
                              void* d_out, int out_size, void* d_ws, size_t ws_size,
                              hipStream_t stream) {
    const float* x = (const float*)d_in[0];   // [32768,1024]
    const float* W = (const float*)d_in[1];   // [1024,128]
    const float* b = (const float*)d_in[2];   // [128]
    float* out     = (float*)d_out;           // [32768,128]
    __bf16* wsW    = (__bf16*)d_ws;           // 256 KB swizzled bf16 W

    prep_w<<<DIM * NT / 256, 256, 0, stream>>>(W, wsW);
    gemm_bias_sigmoid<<<BATCH / 64, 256, 0, stream>>>(
        x, (const __hip_bfloat16*)wsW, b, out);
}